// Round 15
// baseline (339.972 us; speedup 1.0000x reference)
//
#include <hip/hip_runtime.h>

// Encoder: emb-gather(pre-split f16 hi/lo) -> fused mm16p2 xp matmuls -> BiGRU
// scan -> mm16s_wt -> fused mm16p2 dt/td -> tree scans -> fc.
// r15 scans: IN-WAVE quarter reduction, single chain. lane = q2*16+j4, so a
// column's 4 k-quarter partials live in one wave -> 2x shfl_xor replaces the
// part[] LDS round-trip; ONE barrier/step (gru h2 double-buffered; tree rows
// read != rows written within a step); activations spread over 8 waves.
// r13's regression is attributed to dual-chain (VGPR cap hit + 2x VALU work),
// not the in-wave reduce -- this isolates the reduce. Weights/stream = r12.

typedef _Float16 half2v __attribute__((ext_vector_type(2)));
typedef _Float16 half8 __attribute__((ext_vector_type(8)));
typedef unsigned int u32x32 __attribute__((ext_vector_type(32)));
typedef float f32x4v __attribute__((ext_vector_type(4)));

__device__ __forceinline__ float fdot2f(unsigned a, unsigned b, float c) {
#if __has_builtin(__builtin_amdgcn_fdot2)
  return __builtin_amdgcn_fdot2(__builtin_bit_cast(half2v, a),
                                __builtin_bit_cast(half2v, b), c, false);
#else
  half2v av = __builtin_bit_cast(half2v, a), bv = __builtin_bit_cast(half2v, b);
  return c + (float)av.x * (float)bv.x + (float)av.y * (float)bv.y;
#endif
}

__device__ __forceinline__ unsigned packh2(float x, float y) {
  half2v p;
  p.x = (_Float16)x;
  p.y = (_Float16)y;
  return __builtin_bit_cast(unsigned, p);
}
__device__ __forceinline__ unsigned short f2u(float x) {
  return __builtin_bit_cast(unsigned short, (_Float16)x);
}
__device__ __forceinline__ float sigm(float x) { return 1.f / (1.f + __expf(-x)); }
__device__ __forceinline__ float tanh_fast(float x) {
  float cx = fminf(fmaxf(x, -15.f), 15.f);
  float e = __expf(2.f * cx);
  return (e - 1.f) / (e + 1.f);
}

#define RED2(v)                                                                \
  v += __shfl_xor(v, 16);                                                      \
  v += __shfl_xor(v, 32);

// ---- pack recurrent weights (r9 verbatim) ----
__global__ __launch_bounds__(256) void pack_w(const float* __restrict__ W0,
                                              const float* __restrict__ W1,
                                              const float* __restrict__ W2,
                                              const float* __restrict__ W3, unsigned* P0,
                                              unsigned* P1, unsigned* P2, unsigned* P3) {
  const float* W;
  unsigned* P;
  switch (blockIdx.y) {
    case 0: W = W0; P = P0; break;
    case 1: W = W1; P = P1; break;
    case 2: W = W2; P = P2; break;
    default: W = W3; P = P3; break;
  }
  const int tid = blockIdx.x * 256 + threadIdx.x;
  const int i = tid & 3;
  const int u4 = tid >> 2;
  const int jg = u4 & 127;
  const int d4q = u4 >> 7;
  const int d4 = d4q % 48;
  const int q2 = d4q / 48;
  const int col2 = d4 / 24;
  const int rr = d4 % 24;
  const int g = rr >> 3;
  const int p4 = rr & 7;
  const int kp = p4 * 4 + i;
  const int k = q2 * 64 + kp * 2;
  const int col = g * 256 + col2 * 128 + jg;
  P[tid] = packh2(W[(size_t)k * 768 + col], W[(size_t)(k + 1) * 768 + col]);
}

// ---- transpose + hi/lo split, 2 matrices per dispatch (r12 verbatim) ----
__global__ __launch_bounds__(256) void tsplit2(const float* __restrict__ W0,
                                               const float* __restrict__ W1,
                                               unsigned short* __restrict__ H0,
                                               unsigned short* __restrict__ L0,
                                               unsigned short* __restrict__ H1,
                                               unsigned short* __restrict__ L1, int K,
                                               int N) {
  const float* __restrict__ W = blockIdx.z ? W1 : W0;
  unsigned short* __restrict__ WThi = blockIdx.z ? H1 : H0;
  unsigned short* __restrict__ WTlo = blockIdx.z ? L1 : L0;
  __shared__ float T[32][33];
  const int ky = blockIdx.y * 32, nx = blockIdx.x * 32;
  const int r = threadIdx.x >> 3, c4 = (threadIdx.x & 7) * 4;
  float4 v = *(const float4*)(W + (size_t)(ky + r) * N + nx + c4);
  T[r][c4 + 0] = v.x;
  T[r][c4 + 1] = v.y;
  T[r][c4 + 2] = v.z;
  T[r][c4 + 3] = v.w;
  __syncthreads();
  float f[4] = {T[c4 + 0][r], T[c4 + 1][r], T[c4 + 2][r], T[c4 + 3][r]};
  ushort4 oh, ol;
  {
    _Float16 h0 = (_Float16)f[0], h1 = (_Float16)f[1], h2 = (_Float16)f[2],
             h3 = (_Float16)f[3];
    oh.x = __builtin_bit_cast(unsigned short, h0);
    oh.y = __builtin_bit_cast(unsigned short, h1);
    oh.z = __builtin_bit_cast(unsigned short, h2);
    oh.w = __builtin_bit_cast(unsigned short, h3);
    ol.x = f2u(f[0] - (float)h0);
    ol.y = f2u(f[1] - (float)h1);
    ol.z = f2u(f[2] - (float)h2);
    ol.w = f2u(f[3] - (float)h3);
  }
  *(ushort4*)(WThi + (size_t)(nx + r) * K + ky + c4) = oh;
  *(ushort4*)(WTlo + (size_t)(nx + r) * K + ky + c4) = ol;
}

// ---- embedding gathers (r10 verbatim) ----
__global__ void gather_emb_hl(const int* __restrict__ xs, const int* __restrict__ labels,
                              const float* __restrict__ embW,
                              unsigned short* __restrict__ eHi,
                              unsigned short* __restrict__ eLo) {
  const int row = blockIdx.x, t = threadIdx.x;  // 128 thr
  const float4* W4 = (const float4*)embW;
  const int src = (t < 64) ? xs[row] : labels[row];
  float4 v = W4[(size_t)src * 64 + (t & 63)];
  float f[4] = {v.x, v.y, v.z, v.w};
  ushort4 oh, ol;
  _Float16 h0 = (_Float16)f[0], h1 = (_Float16)f[1], h2 = (_Float16)f[2],
           h3 = (_Float16)f[3];
  oh.x = __builtin_bit_cast(unsigned short, h0);
  oh.y = __builtin_bit_cast(unsigned short, h1);
  oh.z = __builtin_bit_cast(unsigned short, h2);
  oh.w = __builtin_bit_cast(unsigned short, h3);
  ol.x = f2u(f[0] - (float)h0);
  ol.y = f2u(f[1] - (float)h1);
  ol.z = f2u(f[2] - (float)h2);
  ol.w = f2u(f[3] - (float)h3);
  const size_t idx = (size_t)row * 512 + (t >> 6) * 256 + (t & 63) * 4;
  *(ushort4*)(eHi + idx) = oh;
  *(ushort4*)(eLo + idx) = ol;
}

__global__ void gather_rel_hl(const int* __restrict__ rels,
                              const float* __restrict__ relW,
                              unsigned short* __restrict__ oHi,
                              unsigned short* __restrict__ oLo) {
  const int row = blockIdx.x, t = threadIdx.x;  // 64 thr
  const float4* W4 = (const float4*)relW;
  float4 v = W4[(size_t)rels[row] * 64 + t];
  float f[4] = {v.x, v.y, v.z, v.w};
  ushort4 oh, ol;
  _Float16 h0 = (_Float16)f[0], h1 = (_Float16)f[1], h2 = (_Float16)f[2],
           h3 = (_Float16)f[3];
  oh.x = __builtin_bit_cast(unsigned short, h0);
  oh.y = __builtin_bit_cast(unsigned short, h1);
  oh.z = __builtin_bit_cast(unsigned short, h2);
  oh.w = __builtin_bit_cast(unsigned short, h3);
  ol.x = f2u(f[0] - (float)h0);
  ol.y = f2u(f[1] - (float)h1);
  ol.z = f2u(f[2] - (float)h2);
  ol.w = f2u(f[3] - (float)h3);
  const size_t idx = (size_t)row * 512 + 256 + t * 4;
  *(ushort4*)(oHi + idx) = oh;
  *(ushort4*)(oLo + idx) = ol;
}

// ---- fused pre-split MFMA GEMM pair (r14 verbatim) ----
__global__ __launch_bounds__(256) void mm16p2(
    const unsigned short* __restrict__ Ahi, const unsigned short* __restrict__ Alo,
    const unsigned short* __restrict__ B0h, const unsigned short* __restrict__ B0l,
    const float* __restrict__ bias0, float* __restrict__ C0,
    const unsigned short* __restrict__ B1h, const unsigned short* __restrict__ B1l,
    const float* __restrict__ bias1, float* __restrict__ C1, int ldc) {
  const unsigned short* __restrict__ Bhi = blockIdx.z ? B1h : B0h;
  const unsigned short* __restrict__ Blo = blockIdx.z ? B1l : B0l;
  const float* __restrict__ bias = blockIdx.z ? bias1 : bias0;
  float* __restrict__ Cf = blockIdx.z ? C1 : C0;
  __shared__ __align__(16) _Float16 As_h[64][40], As_l[64][40];
  __shared__ __align__(16) _Float16 Bs_h[64][40], Bs_l[64][40];
  const int t = threadIdx.x, l = t & 63, w = t >> 6;
  const int bm = blockIdx.y * 64, bn = blockIdx.x * 64;
  const int sr = t >> 2, sc = (t & 3) * 8;
  f32x4v ac0 = {0.f, 0.f, 0.f, 0.f}, ac1 = ac0, ac2 = ac0, ac3 = ac0;
  const int fr = w * 16 + (l & 15), fc = (l >> 4) * 8, lo16 = l & 15;
  for (int kt = 0; kt < 512; kt += 32) {
    *(uint4*)(&As_h[sr][sc]) = *(const uint4*)(Ahi + (size_t)(bm + sr) * 512 + kt + sc);
    *(uint4*)(&As_l[sr][sc]) = *(const uint4*)(Alo + (size_t)(bm + sr) * 512 + kt + sc);
    *(uint4*)(&Bs_h[sr][sc]) = *(const uint4*)(Bhi + (size_t)(bn + sr) * 512 + kt + sc);
    *(uint4*)(&Bs_l[sr][sc]) = *(const uint4*)(Blo + (size_t)(bn + sr) * 512 + kt + sc);
    __syncthreads();
    half8 avh = __builtin_bit_cast(half8, *(const uint4*)(&As_h[fr][fc]));
    half8 avl = __builtin_bit_cast(half8, *(const uint4*)(&As_l[fr][fc]));
#define BH(NT) __builtin_bit_cast(half8, *(const uint4*)(&Bs_h[(NT)*16 + lo16][fc]))
#define BL(NT) __builtin_bit_cast(half8, *(const uint4*)(&Bs_l[(NT)*16 + lo16][fc]))
    half8 b0h = BH(0), b1h = BH(1), b2h = BH(2), b3h = BH(3);
    half8 b0l = BL(0), b1l = BL(1), b2l = BL(2), b3l = BL(3);
#undef BH
#undef BL
    ac0 = __builtin_amdgcn_mfma_f32_16x16x32_f16(avh, b0h, ac0, 0, 0, 0);
    ac1 = __builtin_amdgcn_mfma_f32_16x16x32_f16(avh, b1h, ac1, 0, 0, 0);
    ac2 = __builtin_amdgcn_mfma_f32_16x16x32_f16(avh, b2h, ac2, 0, 0, 0);
    ac3 = __builtin_amdgcn_mfma_f32_16x16x32_f16(avh, b3h, ac3, 0, 0, 0);
    ac0 = __builtin_amdgcn_mfma_f32_16x16x32_f16(avh, b0l, ac0, 0, 0, 0);
    ac1 = __builtin_amdgcn_mfma_f32_16x16x32_f16(avh, b1l, ac1, 0, 0, 0);
    ac2 = __builtin_amdgcn_mfma_f32_16x16x32_f16(avh, b2l, ac2, 0, 0, 0);
    ac3 = __builtin_amdgcn_mfma_f32_16x16x32_f16(avh, b3l, ac3, 0, 0, 0);
    ac0 = __builtin_amdgcn_mfma_f32_16x16x32_f16(avl, b0h, ac0, 0, 0, 0);
    ac1 = __builtin_amdgcn_mfma_f32_16x16x32_f16(avl, b1h, ac1, 0, 0, 0);
    ac2 = __builtin_amdgcn_mfma_f32_16x16x32_f16(avl, b2h, ac2, 0, 0, 0);
    ac3 = __builtin_amdgcn_mfma_f32_16x16x32_f16(avl, b3h, ac3, 0, 0, 0);
    __syncthreads();
  }
  const int hi4 = l >> 4;
#define EPI(AC, NT)                                                            \
  {                                                                            \
    _Pragma("unroll") for (int i = 0; i < 4; ++i) {                            \
      const int row = bm + w * 16 + hi4 * 4 + i;                               \
      const int col = bn + (NT)*16 + lo16;                                     \
      Cf[(size_t)row * ldc + col] = (AC)[i] + bias[col];                       \
    }                                                                          \
  }
  EPI(ac0, 0) EPI(ac1, 1) EPI(ac2, 2) EPI(ac3, 3)
#undef EPI
}

// ---- inline-split MFMA for the Wt matmul (r10 verbatim) ----
__global__ __launch_bounds__(256) void mm16s_wt(const float* __restrict__ A,
                                                const float* __restrict__ W,
                                                const float* __restrict__ bias,
                                                unsigned short* __restrict__ CHi,
                                                unsigned short* __restrict__ CLo, int N,
                                                int ldc) {
  __shared__ __align__(16) _Float16 Ahi[64][40], Alo[64][40];
  __shared__ __align__(16) _Float16 Bhi[64][40], Blo[64][40];
  const int t = threadIdx.x, l = t & 63, w = t >> 6;
  const int bm = blockIdx.y * 64, bn = blockIdx.x * 64;
  const int ar = t >> 2, ac8 = (t & 3) * 8;
  const int bk = t >> 3, bn8 = (t & 7) * 8;
  f32x4v ac0 = {0.f, 0.f, 0.f, 0.f}, ac1 = ac0, ac2 = ac0, ac3 = ac0;
  const int fr = w * 16 + (l & 15), fc = (l >> 4) * 8, lo16 = l & 15;
  for (int kt = 0; kt < 512; kt += 32) {
    {
      const float* ap = A + (size_t)(bm + ar) * 512 + kt + ac8;
      float4 v0 = *(const float4*)ap;
      float4 v1 = *(const float4*)(ap + 4);
      float av[8] = {v0.x, v0.y, v0.z, v0.w, v1.x, v1.y, v1.z, v1.w};
#pragma unroll
      for (int i = 0; i < 8; ++i) {
        _Float16 h = (_Float16)av[i];
        Ahi[ar][ac8 + i] = h;
        Alo[ar][ac8 + i] = (_Float16)(av[i] - (float)h);
      }
    }
    {
      const float* wp = W + (size_t)(kt + bk) * N + bn + bn8;
      float4 v0 = *(const float4*)wp;
      float4 v1 = *(const float4*)(wp + 4);
      float wv[8] = {v0.x, v0.y, v0.z, v0.w, v1.x, v1.y, v1.z, v1.w};
#pragma unroll
      for (int i = 0; i < 8; ++i) {
        _Float16 h = (_Float16)wv[i];
        Bhi[bn8 + i][bk] = h;
        Blo[bn8 + i][bk] = (_Float16)(wv[i] - (float)h);
      }
    }
    __syncthreads();
    half8 avh = __builtin_bit_cast(half8, *(const uint4*)(&Ahi[fr][fc]));
    half8 avl = __builtin_bit_cast(half8, *(const uint4*)(&Alo[fr][fc]));
#define BH(NT) __builtin_bit_cast(half8, *(const uint4*)(&Bhi[(NT)*16 + lo16][fc]))
#define BL(NT) __builtin_bit_cast(half8, *(const uint4*)(&Blo[(NT)*16 + lo16][fc]))
    half8 b0h = BH(0), b1h = BH(1), b2h = BH(2), b3h = BH(3);
    half8 b0l = BL(0), b1l = BL(1), b2l = BL(2), b3l = BL(3);
#undef BH
#undef BL
    ac0 = __builtin_amdgcn_mfma_f32_16x16x32_f16(avh, b0h, ac0, 0, 0, 0);
    ac1 = __builtin_amdgcn_mfma_f32_16x16x32_f16(avh, b1h, ac1, 0, 0, 0);
    ac2 = __builtin_amdgcn_mfma_f32_16x16x32_f16(avh, b2h, ac2, 0, 0, 0);
    ac3 = __builtin_amdgcn_mfma_f32_16x16x32_f16(avh, b3h, ac3, 0, 0, 0);
    ac0 = __builtin_amdgcn_mfma_f32_16x16x32_f16(avh, b0l, ac0, 0, 0, 0);
    ac1 = __builtin_amdgcn_mfma_f32_16x16x32_f16(avh, b1l, ac1, 0, 0, 0);
    ac2 = __builtin_amdgcn_mfma_f32_16x16x32_f16(avh, b2l, ac2, 0, 0, 0);
    ac3 = __builtin_amdgcn_mfma_f32_16x16x32_f16(avh, b3l, ac3, 0, 0, 0);
    ac0 = __builtin_amdgcn_mfma_f32_16x16x32_f16(avl, b0h, ac0, 0, 0, 0);
    ac1 = __builtin_amdgcn_mfma_f32_16x16x32_f16(avl, b1h, ac1, 0, 0, 0);
    ac2 = __builtin_amdgcn_mfma_f32_16x16x32_f16(avl, b2h, ac2, 0, 0, 0);
    ac3 = __builtin_amdgcn_mfma_f32_16x16x32_f16(avl, b3h, ac3, 0, 0, 0);
    __syncthreads();
  }
  const int hi4 = l >> 4;
#define EPI(AC, NT)                                                            \
  {                                                                            \
    _Pragma("unroll") for (int i = 0; i < 4; ++i) {                            \
      const int row = bm + w * 16 + hi4 * 4 + i;                               \
      const int col = bn + (NT)*16 + lo16;                                     \
      float v = (AC)[i] + bias[col];                                           \
      _Float16 h = (_Float16)v;                                                \
      CHi[(size_t)row * ldc + col] = __builtin_bit_cast(unsigned short, h);    \
      CLo[(size_t)row * ldc + col] = f2u(v - (float)h);                        \
    }                                                                          \
  }
  EPI(ac0, 0) EPI(ac1, 1) EPI(ac2, 2) EPI(ac3, 3)
#undef EPI
}

// ---- scan helpers (r9 verbatim; mapping-agnostic: indexed by q2, jg, t) ----
template <int NP>
__device__ __forceinline__ void stage_w(const uint4* __restrict__ P4, int q2, int jg,
                                        int t, uint2 (*Wl)[512], u32x32& w0, u32x32& w1,
                                        u32x32& w2) {
#pragma unroll
  for (int p4 = 0; p4 < 8; ++p4) {
    uint4 v0 = P4[(q2 * 48 + p4) * 128 + jg];
    w0[4 * p4 + 0] = v0.x; w0[4 * p4 + 1] = v0.y;
    w0[4 * p4 + 2] = v0.z; w0[4 * p4 + 3] = v0.w;
    uint4 v1 = P4[(q2 * 48 + 8 + p4) * 128 + jg];
    w1[4 * p4 + 0] = v1.x; w1[4 * p4 + 1] = v1.y;
    w1[4 * p4 + 2] = v1.z; w1[4 * p4 + 3] = v1.w;
    uint4 v2 = P4[(q2 * 48 + 16 + p4) * 128 + jg];
    w2[4 * p4 + 0] = v2.x; w2[4 * p4 + 1] = v2.y;
    w2[4 * p4 + 2] = v2.z; w2[4 * p4 + 3] = v2.w;
  }
#pragma unroll
  for (int g = 0; g < 3; ++g)
#pragma unroll
    for (int p4 = 0; p4 < NP; ++p4) {
      uint4 v = P4[(q2 * 48 + 24 + g * 8 + p4) * 128 + jg];
      Wl[(g * NP + p4) * 2 + 0][t] = make_uint2(v.x, v.y);
      Wl[(g * NP + p4) * 2 + 1][t] = make_uint2(v.z, v.w);
    }
}

template <int NP>
__device__ __forceinline__ void dot_step(const u32x32& w0, const u32x32& w1,
                                         const u32x32& w2, const uint2 (*Wl)[512], int t,
                                         const uint4* __restrict__ P4, int sb,
                                         const uint4* hv4, float& a0, float& a1,
                                         float& a2, float& a3, float& a4, float& a5) {
#pragma unroll
  for (int c = 0; c < 8; ++c) {
    uint4 hu = hv4[c];
    a0 = fdot2f(w0[4 * c + 0], hu.x, a0); a0 = fdot2f(w0[4 * c + 1], hu.y, a0);
    a0 = fdot2f(w0[4 * c + 2], hu.z, a0); a0 = fdot2f(w0[4 * c + 3], hu.w, a0);
    a1 = fdot2f(w1[4 * c + 0], hu.x, a1); a1 = fdot2f(w1[4 * c + 1], hu.y, a1);
    a1 = fdot2f(w1[4 * c + 2], hu.z, a1); a1 = fdot2f(w1[4 * c + 3], hu.w, a1);
    a2 = fdot2f(w2[4 * c + 0], hu.x, a2); a2 = fdot2f(w2[4 * c + 1], hu.y, a2);
    a2 = fdot2f(w2[4 * c + 2], hu.z, a2); a2 = fdot2f(w2[4 * c + 3], hu.w, a2);
    if (c < NP) {
      uint2 u0 = Wl[(0 * NP + c) * 2 + 0][t], u1 = Wl[(0 * NP + c) * 2 + 1][t];
      a3 = fdot2f(u0.x, hu.x, a3); a3 = fdot2f(u0.y, hu.y, a3);
      a3 = fdot2f(u1.x, hu.z, a3); a3 = fdot2f(u1.y, hu.w, a3);
      uint2 v0 = Wl[(1 * NP + c) * 2 + 0][t], v1 = Wl[(1 * NP + c) * 2 + 1][t];
      a4 = fdot2f(v0.x, hu.x, a4); a4 = fdot2f(v0.y, hu.y, a4);
      a4 = fdot2f(v1.x, hu.z, a4); a4 = fdot2f(v1.y, hu.w, a4);
      uint2 x0 = Wl[(2 * NP + c) * 2 + 0][t], x1 = Wl[(2 * NP + c) * 2 + 1][t];
      a5 = fdot2f(x0.x, hu.x, a5); a5 = fdot2f(x0.y, hu.y, a5);
      a5 = fdot2f(x1.x, hu.z, a5); a5 = fdot2f(x1.y, hu.w, a5);
    } else {
      uint4 s0 = P4[sb + (0 * 8 + c) * 128];
      a3 = fdot2f(s0.x, hu.x, a3); a3 = fdot2f(s0.y, hu.y, a3);
      a3 = fdot2f(s0.z, hu.z, a3); a3 = fdot2f(s0.w, hu.w, a3);
      uint4 s1 = P4[sb + (1 * 8 + c) * 128];
      a4 = fdot2f(s1.x, hu.x, a4); a4 = fdot2f(s1.y, hu.y, a4);
      a4 = fdot2f(s1.z, hu.z, a4); a4 = fdot2f(s1.w, hu.w, a4);
      uint4 s2 = P4[sb + (2 * 8 + c) * 128];
      a5 = fdot2f(s2.x, hu.x, a5); a5 = fdot2f(s2.y, hu.y, a5);
      a5 = fdot2f(s2.z, hu.z, a5); a5 = fdot2f(s2.w, hu.w, a5);
    }
  }
}

// ---------------- BiGRU scan: in-wave reduce, 1 barrier/step ----------------
__global__ __launch_bounds__(512) void gru_scan_w(
    const unsigned* __restrict__ Pf, const unsigned* __restrict__ Pb,
    const float* __restrict__ bh_f, const float* __restrict__ bh_b,
    const float* __restrict__ xp_f, const float* __restrict__ xp_b,
    float* __restrict__ grus) {
  const int b = blockIdx.x & 31, dir = blockIdx.x >> 5;
  const uint4* __restrict__ P4 = (const uint4*)(dir ? Pb : Pf);
  const float* __restrict__ bh = dir ? bh_b : bh_f;
  const float* __restrict__ xp = dir ? xp_b : xp_f;

  __shared__ uint2 Wl[36][512];                  // NP=6
  __shared__ __align__(16) unsigned h2[2][128];  // double-buffered packed h

  const int t = threadIdx.x;
  const int lane = t & 63, wv = t >> 6;
  const int q2 = lane >> 4;              // k-quarter, in-wave
  const int jg = (lane & 15) + wv * 16;  // 0..127
  const int sb = (q2 * 48 + 24) * 128 + jg;

  u32x32 w0, w1, w2;
  stage_w<6>(P4, q2, jg, t, Wl, w0, w1, w2);

  const bool actv = (q2 == 0);
  float br0 = 0, bz0 = 0, bn0 = 0, br1 = 0, bz1 = 0, bn1 = 0;
  float hc0 = 0.f, hc1 = 0.f;  // running h for cols jg, jg+128
  if (actv) {
    br0 = bh[jg];       bz0 = bh[256 + jg]; bn0 = bh[512 + jg];
    br1 = bh[128 + jg]; bz1 = bh[384 + jg]; bn1 = bh[640 + jg];
  }
  if (t < 256) ((unsigned*)h2)[t] = 0u;
  __syncthreads();

  for (int s = 0; s < 64; ++s) {
    const int nn = dir ? (63 - s) : s;
    const int rb = s & 1;
    float x0, x1, x2, x3, x4, x5;
    if (actv) {
      const float* xr = xp + (size_t)(b * 64 + nn) * 768;
      x0 = xr[jg];       x1 = xr[256 + jg]; x2 = xr[512 + jg];
      x3 = xr[128 + jg]; x4 = xr[384 + jg]; x5 = xr[640 + jg];
    }
    float a0 = 0.f, a1 = 0.f, a2 = 0.f, a3 = 0.f, a4 = 0.f, a5 = 0.f;
    dot_step<6>(w0, w1, w2, Wl, t, P4, sb, (const uint4*)(&h2[rb][q2 * 32]), a0, a1, a2,
                a3, a4, a5);
    RED2(a0) RED2(a1) RED2(a2) RED2(a3) RED2(a4) RED2(a5)
    if (actv) {
      {
        float r = sigm(x0 + a0 + br0), z = sigm(x1 + a1 + bz0);
        float n = tanh_fast(x2 + r * (a2 + bn0));
        hc0 = (1.f - z) * n + z * hc0;
      }
      {
        float r = sigm(x3 + a3 + br1), z = sigm(x4 + a4 + bz1);
        float n = tanh_fast(x5 + r * (a5 + bn1));
        hc1 = (1.f - z) * n + z * hc1;
      }
      grus[(size_t)(b * 64 + nn) * 512 + dir * 256 + jg] = hc0;
      grus[(size_t)(b * 64 + nn) * 512 + dir * 256 + 128 + jg] = hc1;
      float p0 = __shfl_xor(hc0, 1), p1 = __shfl_xor(hc1, 1);
      if ((jg & 1) == 0) {
        h2[rb ^ 1][jg >> 1] = packh2(hc0, p0);
        h2[rb ^ 1][64 + (jg >> 1)] = packh2(hc1, p1);
      }
    }
    __syncthreads();
  }
}

// ---------------- tree scans: in-wave reduce, S in global, 1 barrier/step ----------------
__global__ __launch_bounds__(512) void tree_scan_w(
    const unsigned* __restrict__ Pdt, const unsigned* __restrict__ Ptd,
    const float* __restrict__ xp_dt, const float* __restrict__ xp_td,
    const int* __restrict__ heads, float* __restrict__ ctx, float* __restrict__ Sg) {
  const int b = blockIdx.x & 31, istd = blockIdx.x >> 5;
  const uint4* __restrict__ P4 = (const uint4*)(istd ? Ptd : Pdt);
  const float* __restrict__ xp = istd ? xp_td : xp_dt;
  float* __restrict__ S = Sg + (size_t)blockIdx.x * 16384;  // [64][256] f32

  __shared__ __align__(16) unsigned S2[65][128];  // packed f16 mirror; row 64 = zeros
  __shared__ uint2 Wl[24][512];                   // NP=4
  __shared__ int hd[64];

  const int t = threadIdx.x;
  const int lane = t & 63, wv = t >> 6;
  const int q2 = lane >> 4;
  const int jg = (lane & 15) + wv * 16;
  const int sb = (q2 * 48 + 24) * 128 + jg;

  u32x32 w0, w1, w2;
  stage_w<4>(P4, q2, jg, t, Wl, w0, w1, w2);

  for (int i = t; i < 16384; i += 512) S[i] = 0.f;
  for (int i = t; i < 65 * 128; i += 512) (&S2[0][0])[i] = 0u;
  if (t < 64) hd[t] = heads[b * 64 + t];
  __syncthreads();

  const bool actv = (q2 == 0);
  float mx0 = -1e30f, mx1 = -1e30f;

  for (int s = 0; s < 64; ++s) {
    const int idx = istd ? s : (63 - s);
    const int par = hd[idx];
    const int srow = istd ? (par >= 0 ? par : 64) : idx;

    float x0, x1, x2, x3, x4, x5;
    float hp0 = 0.f, hp1 = 0.f, acc0 = 0.f, acc1 = 0.f;
    if (actv) {
      const float* xr = xp + (size_t)(b * 64 + idx) * 768;
      x0 = xr[jg];       x1 = xr[256 + jg]; x2 = xr[512 + jg];
      x3 = xr[128 + jg]; x4 = xr[384 + jg]; x5 = xr[640 + jg];
      if (istd) {
        if (par >= 0) {
          hp0 = S[par * 256 + jg];
          hp1 = S[par * 256 + 128 + jg];
        }
      } else {
        hp0 = S[idx * 256 + jg];
        hp1 = S[idx * 256 + 128 + jg];
        if (par >= 0) {
          acc0 = S[par * 256 + jg];
          acc1 = S[par * 256 + 128 + jg];
        }
      }
    }
    float a0 = 0.f, a1 = 0.f, a2 = 0.f, a3 = 0.f, a4 = 0.f, a5 = 0.f;
    dot_step<4>(w0, w1, w2, Wl, t, P4, sb, (const uint4*)(&S2[srow][q2 * 32]), a0, a1,
                a2, a3, a4, a5);
    RED2(a0) RED2(a1) RED2(a2) RED2(a3) RED2(a4) RED2(a5)
    if (actv) {
      float h0, h1;
      {
        float r = sigm(x0 + a0), z = sigm(x1 + a1);
        float n = tanh_fast(x2 + r * a2);
        h0 = (1.f - z) * n + z * hp0;
      }
      {
        float r = sigm(x3 + a3), z = sigm(x4 + a4);
        float n = tanh_fast(x5 + r * a5);
        h1 = (1.f - z) * n + z * hp1;
      }
      mx0 = fmaxf(mx0, h0);
      mx1 = fmaxf(mx1, h1);
      if (istd) {
        // write row idx (!= srow=par<idx... actually par<idx? td reads par, writes idx)
        S[idx * 256 + jg] = h0;
        S[idx * 256 + 128 + jg] = h1;
        float p0 = __shfl_xor(h0, 1), p1 = __shfl_xor(h1, 1);
        if ((jg & 1) == 0) {
          S2[idx][jg >> 1] = packh2(h0, p0);
          S2[idx][64 + (jg >> 1)] = packh2(h1, p1);
        }
      } else if (par >= 0) {
        // write row par (par < idx = srow) -- disjoint from this step's reads
        float c0 = acc0 + h0, c1 = acc1 + h1;
        S[par * 256 + jg] = c0;
        S[par * 256 + 128 + jg] = c1;
        float p0 = __shfl_xor(c0, 1), p1 = __shfl_xor(c1, 1);
        if ((jg & 1) == 0) {
          S2[par][jg >> 1] = packh2(c0, p0);
          S2[par][64 + (jg >> 1)] = packh2(c1, p1);
        }
      }
    }
    __syncthreads();
  }

  if (actv) {
    ctx[(size_t)b * 512 + istd * 256 + jg] = mx0;
    ctx[(size_t)b * 512 + istd * 256 + 128 + jg] = mx1;
  }
}

// ---- fc1 + fc2 ----
__global__ __launch_bounds__(128) void final_k(const float* __restrict__ ctx_g,
                                               const float* __restrict__ fcW,
                                               const float* __restrict__ fcb,
                                               const float* __restrict__ fc2W,
                                               const float* __restrict__ fc2b,
                                               float* __restrict__ out) {
  const int b = blockIdx.x, t = threadIdx.x;
  __shared__ float ctx[512];
  __shared__ float f1[100];
  for (int i = t; i < 512; i += 128) ctx[i] = ctx_g[(size_t)b * 512 + i];
  __syncthreads();
  if (t < 100) {
    float a = fcb[t];
    for (int k = 0; k < 512; ++k) a = fmaf(ctx[k], fcW[k * 100 + t], a);
    f1[t] = a;
  }
  __syncthreads();
  if (t < 5) {
    float a = fc2b[t];
    for (int k = 0; k < 100; ++k) a = fmaf(f1[k], fc2W[k * 5 + t], a);
    out[b * 5 + t] = a;
  }
}

extern "C" void kernel_launch(void* const* d_in, const int* in_sizes, int n_in, void* d_out,
                              int out_size, void* d_ws, size_t ws_size, hipStream_t stream) {
  const int* xs = (const int*)d_in[0];
  const int* heads = (const int*)d_in[1];
  const int* rels = (const int*)d_in[2];
  const int* labels = (const int*)d_in[3];
  const float* emb_W = (const float*)d_in[9];
  const float* rel_W = (const float*)d_in[10];
  const float* Wi_f = (const float*)d_in[11];
  const float* Wh_f = (const float*)d_in[12];
  const float* bi_f = (const float*)d_in[13];
  const float* bh_f = (const float*)d_in[14];
  const float* Wi_b = (const float*)d_in[15];
  const float* Wh_b = (const float*)d_in[16];
  const float* bi_b = (const float*)d_in[17];
  const float* bh_b = (const float*)d_in[18];
  const float* Wt = (const float*)d_in[19];
  const float* bt = (const float*)d_in[20];
  const float* dt_Wx = (const float*)d_in[21];
  const float* dt_Uh = (const float*)d_in[22];
  const float* dt_b = (const float*)d_in[23];
  const float* td_Wx = (const float*)d_in[24];
  const float* td_Uh = (const float*)d_in[25];
  const float* td_b = (const float*)d_in[26];
  const float* fc_W = (const float*)d_in[27];
  const float* fc_b = (const float*)d_in[28];
  const float* fc2_W = (const float*)d_in[29];
  const float* fc2_b = (const float*)d_in[30];

  float* ws = (float*)d_ws;
  float* xp_f = ws;                          // 1572864 f32
  float* xp_b = ws + 1572864;                // 1572864
  float* grus = ws + 3145728;                // 1048576
  float* ctx = ws + 4194304;                 // 16384
  unsigned* P0 = (unsigned*)(ws + 4210688);  // 98304 u32 each
  unsigned* P1 = P0 + 98304;
  unsigned* P2 = P1 + 98304;
  unsigned* P3 = P2 + 98304;
  unsigned short* embHi = (unsigned short*)(ws + 4603904);  // 1048576 u16
  unsigned short* embLo = (unsigned short*)(ws + 5128192);
  unsigned short* WTh_a = (unsigned short*)(ws + 5652480);  // 393216 u16 each
  unsigned short* WTl_a = (unsigned short*)(ws + 5849088);
  unsigned short* WTh_b = (unsigned short*)(ws + 6045696);
  unsigned short* WTl_b = (unsigned short*)(ws + 6242304);
  unsigned short* outHi = embHi;  // alias (emb dead after xp matmuls)
  unsigned short* outLo = embLo;
  float* Sg = ws + 4603904;       // alias: tree f32 state (emb/out dead by then)

  pack_w<<<dim3(384, 4), 256, 0, stream>>>(Wh_f, Wh_b, dt_Uh, td_Uh, P0, P1, P2, P3);
  tsplit2<<<dim3(24, 16, 2), 256, 0, stream>>>(Wi_f, Wi_b, WTh_a, WTl_a, WTh_b, WTl_b,
                                               512, 768);
  gather_emb_hl<<<2048, 128, 0, stream>>>(xs, labels, emb_W, embHi, embLo);
  mm16p2<<<dim3(12, 32, 2), 256, 0, stream>>>(embHi, embLo, WTh_a, WTl_a, bi_f, xp_f,
                                              WTh_b, WTl_b, bi_b, xp_b, 768);
  gru_scan_w<<<64, 512, 0, stream>>>(P0, P1, bh_f, bh_b, xp_f, xp_b, grus);
  tsplit2<<<dim3(24, 16, 2), 256, 0, stream>>>(dt_Wx, td_Wx, WTh_a, WTl_a, WTh_b, WTl_b,
                                               512, 768);
  mm16s_wt<<<dim3(4, 32), 256, 0, stream>>>(grus, Wt, bt, outHi, outLo, 256, 512);
  gather_rel_hl<<<2048, 64, 0, stream>>>(rels, rel_W, outHi, outLo);
  mm16p2<<<dim3(12, 32, 2), 256, 0, stream>>>(outHi, outLo, WTh_a, WTl_a, dt_b, xp_f,
                                              WTh_b, WTl_b, td_b, xp_b, 768);
  tree_scan_w<<<64, 512, 0, stream>>>(P2, P3, xp_f, xp_b, heads, ctx, Sg);
  final_k<<<32, 128, 0, stream>>>(ctx, fc_W, fc_b, fc2_W, fc2_b, (float*)d_out);
}

// Round 16
// 299.367 us; speedup vs baseline: 1.1356x; 1.1356x over previous
//
#include <hip/hip_runtime.h>

// Encoder: emb-gather(pre-split f16 hi/lo) -> fused mm16p2 xp matmuls -> BiGRU
// scan -> mm16s_wt -> fused mm16p2 dt/td -> tree scans -> fc.
// FINAL (r14 verbatim, measured 300.2us): scans are r12 single-block hybrid
// (96 reg dwords + LDS NP + L2 stream, 2 barriers + LDS reduce) -- four
// structural alternatives all measured worse: r11 cross-block sync (6x),
// r13 dual-chain (2.3x), r15 in-wave shfl reduce (+23%), r7 full-stream
// (+80%). ~1.6us/step is the empirical floor for this serial recurrence.

typedef _Float16 half2v __attribute__((ext_vector_type(2)));
typedef _Float16 half8 __attribute__((ext_vector_type(8)));
typedef unsigned int u32x32 __attribute__((ext_vector_type(32)));
typedef float f32x4v __attribute__((ext_vector_type(4)));

__device__ __forceinline__ float fdot2f(unsigned a, unsigned b, float c) {
#if __has_builtin(__builtin_amdgcn_fdot2)
  return __builtin_amdgcn_fdot2(__builtin_bit_cast(half2v, a),
                                __builtin_bit_cast(half2v, b), c, false);
#else
  half2v av = __builtin_bit_cast(half2v, a), bv = __builtin_bit_cast(half2v, b);
  return c + (float)av.x * (float)bv.x + (float)av.y * (float)bv.y;
#endif
}

__device__ __forceinline__ unsigned packh2(float x, float y) {
  half2v p;
  p.x = (_Float16)x;
  p.y = (_Float16)y;
  return __builtin_bit_cast(unsigned, p);
}
__device__ __forceinline__ unsigned short f2u(float x) {
  return __builtin_bit_cast(unsigned short, (_Float16)x);
}
__device__ __forceinline__ float sigm(float x) { return 1.f / (1.f + __expf(-x)); }
__device__ __forceinline__ float tanh_fast(float x) {
  float cx = fminf(fmaxf(x, -15.f), 15.f);
  float e = __expf(2.f * cx);
  return (e - 1.f) / (e + 1.f);
}

// ---- pack recurrent weights ----
__global__ __launch_bounds__(256) void pack_w(const float* __restrict__ W0,
                                              const float* __restrict__ W1,
                                              const float* __restrict__ W2,
                                              const float* __restrict__ W3, unsigned* P0,
                                              unsigned* P1, unsigned* P2, unsigned* P3) {
  const float* W;
  unsigned* P;
  switch (blockIdx.y) {
    case 0: W = W0; P = P0; break;
    case 1: W = W1; P = P1; break;
    case 2: W = W2; P = P2; break;
    default: W = W3; P = P3; break;
  }
  const int tid = blockIdx.x * 256 + threadIdx.x;
  const int i = tid & 3;
  const int u4 = tid >> 2;
  const int jg = u4 & 127;
  const int d4q = u4 >> 7;
  const int d4 = d4q % 48;
  const int q2 = d4q / 48;
  const int col2 = d4 / 24;
  const int rr = d4 % 24;
  const int g = rr >> 3;
  const int p4 = rr & 7;
  const int kp = p4 * 4 + i;
  const int k = q2 * 64 + kp * 2;
  const int col = g * 256 + col2 * 128 + jg;
  P[tid] = packh2(W[(size_t)k * 768 + col], W[(size_t)(k + 1) * 768 + col]);
}

// ---- transpose + hi/lo split, 2 matrices per dispatch ----
__global__ __launch_bounds__(256) void tsplit2(const float* __restrict__ W0,
                                               const float* __restrict__ W1,
                                               unsigned short* __restrict__ H0,
                                               unsigned short* __restrict__ L0,
                                               unsigned short* __restrict__ H1,
                                               unsigned short* __restrict__ L1, int K,
                                               int N) {
  const float* __restrict__ W = blockIdx.z ? W1 : W0;
  unsigned short* __restrict__ WThi = blockIdx.z ? H1 : H0;
  unsigned short* __restrict__ WTlo = blockIdx.z ? L1 : L0;
  __shared__ float T[32][33];
  const int ky = blockIdx.y * 32, nx = blockIdx.x * 32;
  const int r = threadIdx.x >> 3, c4 = (threadIdx.x & 7) * 4;
  float4 v = *(const float4*)(W + (size_t)(ky + r) * N + nx + c4);
  T[r][c4 + 0] = v.x;
  T[r][c4 + 1] = v.y;
  T[r][c4 + 2] = v.z;
  T[r][c4 + 3] = v.w;
  __syncthreads();
  float f[4] = {T[c4 + 0][r], T[c4 + 1][r], T[c4 + 2][r], T[c4 + 3][r]};
  ushort4 oh, ol;
  {
    _Float16 h0 = (_Float16)f[0], h1 = (_Float16)f[1], h2 = (_Float16)f[2],
             h3 = (_Float16)f[3];
    oh.x = __builtin_bit_cast(unsigned short, h0);
    oh.y = __builtin_bit_cast(unsigned short, h1);
    oh.z = __builtin_bit_cast(unsigned short, h2);
    oh.w = __builtin_bit_cast(unsigned short, h3);
    ol.x = f2u(f[0] - (float)h0);
    ol.y = f2u(f[1] - (float)h1);
    ol.z = f2u(f[2] - (float)h2);
    ol.w = f2u(f[3] - (float)h3);
  }
  *(ushort4*)(WThi + (size_t)(nx + r) * K + ky + c4) = oh;
  *(ushort4*)(WTlo + (size_t)(nx + r) * K + ky + c4) = ol;
}

// ---- embedding gathers ----
__global__ void gather_emb_hl(const int* __restrict__ xs, const int* __restrict__ labels,
                              const float* __restrict__ embW,
                              unsigned short* __restrict__ eHi,
                              unsigned short* __restrict__ eLo) {
  const int row = blockIdx.x, t = threadIdx.x;  // 128 thr
  const float4* W4 = (const float4*)embW;
  const int src = (t < 64) ? xs[row] : labels[row];
  float4 v = W4[(size_t)src * 64 + (t & 63)];
  float f[4] = {v.x, v.y, v.z, v.w};
  ushort4 oh, ol;
  _Float16 h0 = (_Float16)f[0], h1 = (_Float16)f[1], h2 = (_Float16)f[2],
           h3 = (_Float16)f[3];
  oh.x = __builtin_bit_cast(unsigned short, h0);
  oh.y = __builtin_bit_cast(unsigned short, h1);
  oh.z = __builtin_bit_cast(unsigned short, h2);
  oh.w = __builtin_bit_cast(unsigned short, h3);
  ol.x = f2u(f[0] - (float)h0);
  ol.y = f2u(f[1] - (float)h1);
  ol.z = f2u(f[2] - (float)h2);
  ol.w = f2u(f[3] - (float)h3);
  const size_t idx = (size_t)row * 512 + (t >> 6) * 256 + (t & 63) * 4;
  *(ushort4*)(eHi + idx) = oh;
  *(ushort4*)(eLo + idx) = ol;
}

__global__ void gather_rel_hl(const int* __restrict__ rels,
                              const float* __restrict__ relW,
                              unsigned short* __restrict__ oHi,
                              unsigned short* __restrict__ oLo) {
  const int row = blockIdx.x, t = threadIdx.x;  // 64 thr
  const float4* W4 = (const float4*)relW;
  float4 v = W4[(size_t)rels[row] * 64 + t];
  float f[4] = {v.x, v.y, v.z, v.w};
  ushort4 oh, ol;
  _Float16 h0 = (_Float16)f[0], h1 = (_Float16)f[1], h2 = (_Float16)f[2],
           h3 = (_Float16)f[3];
  oh.x = __builtin_bit_cast(unsigned short, h0);
  oh.y = __builtin_bit_cast(unsigned short, h1);
  oh.z = __builtin_bit_cast(unsigned short, h2);
  oh.w = __builtin_bit_cast(unsigned short, h3);
  ol.x = f2u(f[0] - (float)h0);
  ol.y = f2u(f[1] - (float)h1);
  ol.z = f2u(f[2] - (float)h2);
  ol.w = f2u(f[3] - (float)h3);
  const size_t idx = (size_t)row * 512 + 256 + t * 4;
  *(ushort4*)(oHi + idx) = oh;
  *(ushort4*)(oLo + idx) = ol;
}

// ---- fused pre-split MFMA GEMM pair: z=0/1 selects {B, bias, C} set ----
__global__ __launch_bounds__(256) void mm16p2(
    const unsigned short* __restrict__ Ahi, const unsigned short* __restrict__ Alo,
    const unsigned short* __restrict__ B0h, const unsigned short* __restrict__ B0l,
    const float* __restrict__ bias0, float* __restrict__ C0,
    const unsigned short* __restrict__ B1h, const unsigned short* __restrict__ B1l,
    const float* __restrict__ bias1, float* __restrict__ C1, int ldc) {
  const unsigned short* __restrict__ Bhi = blockIdx.z ? B1h : B0h;
  const unsigned short* __restrict__ Blo = blockIdx.z ? B1l : B0l;
  const float* __restrict__ bias = blockIdx.z ? bias1 : bias0;
  float* __restrict__ Cf = blockIdx.z ? C1 : C0;
  __shared__ __align__(16) _Float16 As_h[64][40], As_l[64][40];
  __shared__ __align__(16) _Float16 Bs_h[64][40], Bs_l[64][40];
  const int t = threadIdx.x, l = t & 63, w = t >> 6;
  const int bm = blockIdx.y * 64, bn = blockIdx.x * 64;
  const int sr = t >> 2, sc = (t & 3) * 8;
  f32x4v ac0 = {0.f, 0.f, 0.f, 0.f}, ac1 = ac0, ac2 = ac0, ac3 = ac0;
  const int fr = w * 16 + (l & 15), fc = (l >> 4) * 8, lo16 = l & 15;
  for (int kt = 0; kt < 512; kt += 32) {
    *(uint4*)(&As_h[sr][sc]) = *(const uint4*)(Ahi + (size_t)(bm + sr) * 512 + kt + sc);
    *(uint4*)(&As_l[sr][sc]) = *(const uint4*)(Alo + (size_t)(bm + sr) * 512 + kt + sc);
    *(uint4*)(&Bs_h[sr][sc]) = *(const uint4*)(Bhi + (size_t)(bn + sr) * 512 + kt + sc);
    *(uint4*)(&Bs_l[sr][sc]) = *(const uint4*)(Blo + (size_t)(bn + sr) * 512 + kt + sc);
    __syncthreads();
    half8 avh = __builtin_bit_cast(half8, *(const uint4*)(&As_h[fr][fc]));
    half8 avl = __builtin_bit_cast(half8, *(const uint4*)(&As_l[fr][fc]));
#define BH(NT) __builtin_bit_cast(half8, *(const uint4*)(&Bs_h[(NT)*16 + lo16][fc]))
#define BL(NT) __builtin_bit_cast(half8, *(const uint4*)(&Bs_l[(NT)*16 + lo16][fc]))
    half8 b0h = BH(0), b1h = BH(1), b2h = BH(2), b3h = BH(3);
    half8 b0l = BL(0), b1l = BL(1), b2l = BL(2), b3l = BL(3);
#undef BH
#undef BL
    ac0 = __builtin_amdgcn_mfma_f32_16x16x32_f16(avh, b0h, ac0, 0, 0, 0);
    ac1 = __builtin_amdgcn_mfma_f32_16x16x32_f16(avh, b1h, ac1, 0, 0, 0);
    ac2 = __builtin_amdgcn_mfma_f32_16x16x32_f16(avh, b2h, ac2, 0, 0, 0);
    ac3 = __builtin_amdgcn_mfma_f32_16x16x32_f16(avh, b3h, ac3, 0, 0, 0);
    ac0 = __builtin_amdgcn_mfma_f32_16x16x32_f16(avh, b0l, ac0, 0, 0, 0);
    ac1 = __builtin_amdgcn_mfma_f32_16x16x32_f16(avh, b1l, ac1, 0, 0, 0);
    ac2 = __builtin_amdgcn_mfma_f32_16x16x32_f16(avh, b2l, ac2, 0, 0, 0);
    ac3 = __builtin_amdgcn_mfma_f32_16x16x32_f16(avh, b3l, ac3, 0, 0, 0);
    ac0 = __builtin_amdgcn_mfma_f32_16x16x32_f16(avl, b0h, ac0, 0, 0, 0);
    ac1 = __builtin_amdgcn_mfma_f32_16x16x32_f16(avl, b1h, ac1, 0, 0, 0);
    ac2 = __builtin_amdgcn_mfma_f32_16x16x32_f16(avl, b2h, ac2, 0, 0, 0);
    ac3 = __builtin_amdgcn_mfma_f32_16x16x32_f16(avl, b3h, ac3, 0, 0, 0);
    __syncthreads();
  }
  const int hi4 = l >> 4;
#define EPI(AC, NT)                                                            \
  {                                                                            \
    _Pragma("unroll") for (int i = 0; i < 4; ++i) {                            \
      const int row = bm + w * 16 + hi4 * 4 + i;                               \
      const int col = bn + (NT)*16 + lo16;                                     \
      Cf[(size_t)row * ldc + col] = (AC)[i] + bias[col];                       \
    }                                                                          \
  }
  EPI(ac0, 0) EPI(ac1, 1) EPI(ac2, 2) EPI(ac3, 3)
#undef EPI
}

// ---- inline-split MFMA for the Wt matmul ----
__global__ __launch_bounds__(256) void mm16s_wt(const float* __restrict__ A,
                                                const float* __restrict__ W,
                                                const float* __restrict__ bias,
                                                unsigned short* __restrict__ CHi,
                                                unsigned short* __restrict__ CLo, int N,
                                                int ldc) {
  __shared__ __align__(16) _Float16 Ahi[64][40], Alo[64][40];
  __shared__ __align__(16) _Float16 Bhi[64][40], Blo[64][40];
  const int t = threadIdx.x, l = t & 63, w = t >> 6;
  const int bm = blockIdx.y * 64, bn = blockIdx.x * 64;
  const int ar = t >> 2, ac8 = (t & 3) * 8;
  const int bk = t >> 3, bn8 = (t & 7) * 8;
  f32x4v ac0 = {0.f, 0.f, 0.f, 0.f}, ac1 = ac0, ac2 = ac0, ac3 = ac0;
  const int fr = w * 16 + (l & 15), fc = (l >> 4) * 8, lo16 = l & 15;
  for (int kt = 0; kt < 512; kt += 32) {
    {
      const float* ap = A + (size_t)(bm + ar) * 512 + kt + ac8;
      float4 v0 = *(const float4*)ap;
      float4 v1 = *(const float4*)(ap + 4);
      float av[8] = {v0.x, v0.y, v0.z, v0.w, v1.x, v1.y, v1.z, v1.w};
#pragma unroll
      for (int i = 0; i < 8; ++i) {
        _Float16 h = (_Float16)av[i];
        Ahi[ar][ac8 + i] = h;
        Alo[ar][ac8 + i] = (_Float16)(av[i] - (float)h);
      }
    }
    {
      const float* wp = W + (size_t)(kt + bk) * N + bn + bn8;
      float4 v0 = *(const float4*)wp;
      float4 v1 = *(const float4*)(wp + 4);
      float wv[8] = {v0.x, v0.y, v0.z, v0.w, v1.x, v1.y, v1.z, v1.w};
#pragma unroll
      for (int i = 0; i < 8; ++i) {
        _Float16 h = (_Float16)wv[i];
        Bhi[bn8 + i][bk] = h;
        Blo[bn8 + i][bk] = (_Float16)(wv[i] - (float)h);
      }
    }
    __syncthreads();
    half8 avh = __builtin_bit_cast(half8, *(const uint4*)(&Ahi[fr][fc]));
    half8 avl = __builtin_bit_cast(half8, *(const uint4*)(&Alo[fr][fc]));
#define BH(NT) __builtin_bit_cast(half8, *(const uint4*)(&Bhi[(NT)*16 + lo16][fc]))
#define BL(NT) __builtin_bit_cast(half8, *(const uint4*)(&Blo[(NT)*16 + lo16][fc]))
    half8 b0h = BH(0), b1h = BH(1), b2h = BH(2), b3h = BH(3);
    half8 b0l = BL(0), b1l = BL(1), b2l = BL(2), b3l = BL(3);
#undef BH
#undef BL
    ac0 = __builtin_amdgcn_mfma_f32_16x16x32_f16(avh, b0h, ac0, 0, 0, 0);
    ac1 = __builtin_amdgcn_mfma_f32_16x16x32_f16(avh, b1h, ac1, 0, 0, 0);
    ac2 = __builtin_amdgcn_mfma_f32_16x16x32_f16(avh, b2h, ac2, 0, 0, 0);
    ac3 = __builtin_amdgcn_mfma_f32_16x16x32_f16(avh, b3h, ac3, 0, 0, 0);
    ac0 = __builtin_amdgcn_mfma_f32_16x16x32_f16(avh, b0l, ac0, 0, 0, 0);
    ac1 = __builtin_amdgcn_mfma_f32_16x16x32_f16(avh, b1l, ac1, 0, 0, 0);
    ac2 = __builtin_amdgcn_mfma_f32_16x16x32_f16(avh, b2l, ac2, 0, 0, 0);
    ac3 = __builtin_amdgcn_mfma_f32_16x16x32_f16(avh, b3l, ac3, 0, 0, 0);
    ac0 = __builtin_amdgcn_mfma_f32_16x16x32_f16(avl, b0h, ac0, 0, 0, 0);
    ac1 = __builtin_amdgcn_mfma_f32_16x16x32_f16(avl, b1h, ac1, 0, 0, 0);
    ac2 = __builtin_amdgcn_mfma_f32_16x16x32_f16(avl, b2h, ac2, 0, 0, 0);
    ac3 = __builtin_amdgcn_mfma_f32_16x16x32_f16(avl, b3h, ac3, 0, 0, 0);
    __syncthreads();
  }
  const int hi4 = l >> 4;
#define EPI(AC, NT)                                                            \
  {                                                                            \
    _Pragma("unroll") for (int i = 0; i < 4; ++i) {                            \
      const int row = bm + w * 16 + hi4 * 4 + i;                               \
      const int col = bn + (NT)*16 + lo16;                                     \
      float v = (AC)[i] + bias[col];                                           \
      _Float16 h = (_Float16)v;                                                \
      CHi[(size_t)row * ldc + col] = __builtin_bit_cast(unsigned short, h);    \
      CLo[(size_t)row * ldc + col] = f2u(v - (float)h);                        \
    }                                                                          \
  }
  EPI(ac0, 0) EPI(ac1, 1) EPI(ac2, 2) EPI(ac3, 3)
#undef EPI
}

// ---- scan helpers ----
template <int NP>
__device__ __forceinline__ void stage_w(const uint4* __restrict__ P4, int q2, int jg,
                                        int t, uint2 (*Wl)[512], u32x32& w0, u32x32& w1,
                                        u32x32& w2) {
#pragma unroll
  for (int p4 = 0; p4 < 8; ++p4) {
    uint4 v0 = P4[(q2 * 48 + p4) * 128 + jg];
    w0[4 * p4 + 0] = v0.x; w0[4 * p4 + 1] = v0.y;
    w0[4 * p4 + 2] = v0.z; w0[4 * p4 + 3] = v0.w;
    uint4 v1 = P4[(q2 * 48 + 8 + p4) * 128 + jg];
    w1[4 * p4 + 0] = v1.x; w1[4 * p4 + 1] = v1.y;
    w1[4 * p4 + 2] = v1.z; w1[4 * p4 + 3] = v1.w;
    uint4 v2 = P4[(q2 * 48 + 16 + p4) * 128 + jg];
    w2[4 * p4 + 0] = v2.x; w2[4 * p4 + 1] = v2.y;
    w2[4 * p4 + 2] = v2.z; w2[4 * p4 + 3] = v2.w;
  }
#pragma unroll
  for (int g = 0; g < 3; ++g)
#pragma unroll
    for (int p4 = 0; p4 < NP; ++p4) {
      uint4 v = P4[(q2 * 48 + 24 + g * 8 + p4) * 128 + jg];
      Wl[(g * NP + p4) * 2 + 0][t] = make_uint2(v.x, v.y);
      Wl[(g * NP + p4) * 2 + 1][t] = make_uint2(v.z, v.w);
    }
}

template <int NP>
__device__ __forceinline__ void dot_step(const u32x32& w0, const u32x32& w1,
                                         const u32x32& w2, const uint2 (*Wl)[512], int t,
                                         const uint4* __restrict__ P4, int sb,
                                         const uint4* hv4, float& a0, float& a1,
                                         float& a2, float& a3, float& a4, float& a5) {
#pragma unroll
  for (int c = 0; c < 8; ++c) {
    uint4 hu = hv4[c];
    a0 = fdot2f(w0[4 * c + 0], hu.x, a0); a0 = fdot2f(w0[4 * c + 1], hu.y, a0);
    a0 = fdot2f(w0[4 * c + 2], hu.z, a0); a0 = fdot2f(w0[4 * c + 3], hu.w, a0);
    a1 = fdot2f(w1[4 * c + 0], hu.x, a1); a1 = fdot2f(w1[4 * c + 1], hu.y, a1);
    a1 = fdot2f(w1[4 * c + 2], hu.z, a1); a1 = fdot2f(w1[4 * c + 3], hu.w, a1);
    a2 = fdot2f(w2[4 * c + 0], hu.x, a2); a2 = fdot2f(w2[4 * c + 1], hu.y, a2);
    a2 = fdot2f(w2[4 * c + 2], hu.z, a2); a2 = fdot2f(w2[4 * c + 3], hu.w, a2);
    if (c < NP) {
      uint2 u0 = Wl[(0 * NP + c) * 2 + 0][t], u1 = Wl[(0 * NP + c) * 2 + 1][t];
      a3 = fdot2f(u0.x, hu.x, a3); a3 = fdot2f(u0.y, hu.y, a3);
      a3 = fdot2f(u1.x, hu.z, a3); a3 = fdot2f(u1.y, hu.w, a3);
      uint2 v0 = Wl[(1 * NP + c) * 2 + 0][t], v1 = Wl[(1 * NP + c) * 2 + 1][t];
      a4 = fdot2f(v0.x, hu.x, a4); a4 = fdot2f(v0.y, hu.y, a4);
      a4 = fdot2f(v1.x, hu.z, a4); a4 = fdot2f(v1.y, hu.w, a4);
      uint2 x0 = Wl[(2 * NP + c) * 2 + 0][t], x1 = Wl[(2 * NP + c) * 2 + 1][t];
      a5 = fdot2f(x0.x, hu.x, a5); a5 = fdot2f(x0.y, hu.y, a5);
      a5 = fdot2f(x1.x, hu.z, a5); a5 = fdot2f(x1.y, hu.w, a5);
    } else {
      uint4 s0 = P4[sb + (0 * 8 + c) * 128];
      a3 = fdot2f(s0.x, hu.x, a3); a3 = fdot2f(s0.y, hu.y, a3);
      a3 = fdot2f(s0.z, hu.z, a3); a3 = fdot2f(s0.w, hu.w, a3);
      uint4 s1 = P4[sb + (1 * 8 + c) * 128];
      a4 = fdot2f(s1.x, hu.x, a4); a4 = fdot2f(s1.y, hu.y, a4);
      a4 = fdot2f(s1.z, hu.z, a4); a4 = fdot2f(s1.w, hu.w, a4);
      uint4 s2 = P4[sb + (2 * 8 + c) * 128];
      a5 = fdot2f(s2.x, hu.x, a5); a5 = fdot2f(s2.y, hu.y, a5);
      a5 = fdot2f(s2.z, hu.z, a5); a5 = fdot2f(s2.w, hu.w, a5);
    }
  }
}

// ---------------- BiGRU scan ----------------
__global__ __launch_bounds__(512) void gru_scan_h(
    const unsigned* __restrict__ Pf, const unsigned* __restrict__ Pb,
    const float* __restrict__ bh_f, const float* __restrict__ bh_b,
    const float* __restrict__ xp_f, const float* __restrict__ xp_b,
    float* __restrict__ grus) {
  const int b = blockIdx.x & 31, dir = blockIdx.x >> 5;
  const uint4* __restrict__ P4 = (const uint4*)(dir ? Pb : Pf);
  const float* __restrict__ bh = dir ? bh_b : bh_f;
  const float* __restrict__ xp = dir ? xp_b : xp_f;

  __shared__ uint2 Wl[36][512];
  __shared__ float part[4][3][256];
  __shared__ __align__(16) unsigned h2[128];

  const int t = threadIdx.x, jg = t & 127, q2 = t >> 7;
  const int sb = (q2 * 48 + 24) * 128 + jg;

  u32x32 w0, w1, w2;
  stage_w<6>(P4, q2, jg, t, Wl, w0, w1, w2);

  float br0 = 0.f, br1 = 0.f, bz0 = 0.f, bz1 = 0.f, bn0 = 0.f, bn1 = 0.f;
  float hp0 = 0.f, hp1 = 0.f;
  if (t < 128) {
    br0 = bh[2 * t];       br1 = bh[2 * t + 1];
    bz0 = bh[256 + 2 * t]; bz1 = bh[256 + 2 * t + 1];
    bn0 = bh[512 + 2 * t]; bn1 = bh[512 + 2 * t + 1];
    h2[t] = 0u;
  }
  __syncthreads();

  for (int s = 0; s < 64; ++s) {
    const int nn = dir ? (63 - s) : s;
    float2 pxr, pxz, pxn;
    if (t < 128) {
      const float* xrow = xp + (size_t)(b * 64 + nn) * 768;
      pxr = *(const float2*)(xrow + 2 * t);
      pxz = *(const float2*)(xrow + 256 + 2 * t);
      pxn = *(const float2*)(xrow + 512 + 2 * t);
    }
    float a0 = 0.f, a1 = 0.f, a2 = 0.f, a3 = 0.f, a4 = 0.f, a5 = 0.f;
    dot_step<6>(w0, w1, w2, Wl, t, P4, sb, (const uint4*)(h2 + q2 * 32), a0, a1, a2, a3,
                a4, a5);
    part[q2][0][jg] = a0;
    part[q2][0][128 + jg] = a3;
    part[q2][1][jg] = a1;
    part[q2][1][128 + jg] = a4;
    part[q2][2][jg] = a2;
    part[q2][2][128 + jg] = a5;
    __syncthreads();
    if (t < 128) {
      float s0r = 0, s1r = 0, s0z = 0, s1z = 0, s0n = 0, s1n = 0;
#pragma unroll
      for (int q = 0; q < 4; ++q) {
        float2 pr = *(const float2*)(&part[q][0][2 * t]); s0r += pr.x; s1r += pr.y;
        float2 pz = *(const float2*)(&part[q][1][2 * t]); s0z += pz.x; s1z += pz.y;
        float2 pn = *(const float2*)(&part[q][2][2 * t]); s0n += pn.x; s1n += pn.y;
      }
      float r0 = sigm(pxr.x + s0r + br0), r1 = sigm(pxr.y + s1r + br1);
      float z0 = sigm(pxz.x + s0z + bz0), z1 = sigm(pxz.y + s1z + bz1);
      float n0 = tanh_fast(pxn.x + r0 * (s0n + bn0));
      float n1 = tanh_fast(pxn.y + r1 * (s1n + bn1));
      float h0 = (1.f - z0) * n0 + z0 * hp0;
      float h1 = (1.f - z1) * n1 + z1 * hp1;
      hp0 = h0;
      hp1 = h1;
      h2[t] = packh2(h0, h1);
      float2 o;
      o.x = h0;
      o.y = h1;
      *(float2*)(grus + (size_t)(b * 64 + nn) * 512 + dir * 256 + 2 * t) = o;
    }
    __syncthreads();
  }
}

// ---------------- tree scans: S state in GLOBAL, NP=4 ----------------
__global__ __launch_bounds__(512) void tree_scan_g(
    const unsigned* __restrict__ Pdt, const unsigned* __restrict__ Ptd,
    const float* __restrict__ xp_dt, const float* __restrict__ xp_td,
    const int* __restrict__ heads, float* __restrict__ ctx, float* __restrict__ Sg) {
  const int b = blockIdx.x & 31, istd = blockIdx.x >> 5;
  const uint4* __restrict__ P4 = (const uint4*)(istd ? Ptd : Pdt);
  const float* __restrict__ xp = istd ? xp_td : xp_dt;
  float* __restrict__ S = Sg + (size_t)blockIdx.x * 16384;  // [64][256] f32

  __shared__ __align__(16) unsigned S2[65][128];
  __shared__ uint2 Wl[24][512];
  __shared__ float part[4][3][256];
  __shared__ int hd[64];

  const int t = threadIdx.x, jg = t & 127, q2 = t >> 7;
  const int sb = (q2 * 48 + 24) * 128 + jg;

  u32x32 w0, w1, w2;
  stage_w<4>(P4, q2, jg, t, Wl, w0, w1, w2);

  for (int i = t; i < 16384; i += 512) S[i] = 0.f;
  for (int i = t; i < 65 * 128; i += 512) (&S2[0][0])[i] = 0u;
  if (t < 64) hd[t] = heads[b * 64 + t];
  __syncthreads();

  float mx0 = -1e30f, mx1 = -1e30f;

  for (int s = 0; s < 64; ++s) {
    const int idx = istd ? s : (63 - s);
    const int par = hd[idx];
    const int srow = istd ? (par >= 0 ? par : 64) : idx;

    float2 pxr, pxz, pxn;
    float hp0 = 0.f, hp1 = 0.f, acc0 = 0.f, acc1 = 0.f;
    if (t < 128) {
      const float* xrow = xp + (size_t)(b * 64 + idx) * 768;
      pxr = *(const float2*)(xrow + 2 * t);
      pxz = *(const float2*)(xrow + 256 + 2 * t);
      pxn = *(const float2*)(xrow + 512 + 2 * t);
      if (istd) {
        if (par >= 0) {
          float2 v = *(const float2*)(S + par * 256 + 2 * t);
          hp0 = v.x;
          hp1 = v.y;
        }
      } else {
        float2 v = *(const float2*)(S + idx * 256 + 2 * t);
        hp0 = v.x;
        hp1 = v.y;
        if (par >= 0) {
          float2 a = *(const float2*)(S + par * 256 + 2 * t);
          acc0 = a.x;
          acc1 = a.y;
        }
      }
    }
    float a0 = 0.f, a1 = 0.f, a2 = 0.f, a3 = 0.f, a4 = 0.f, a5 = 0.f;
    dot_step<4>(w0, w1, w2, Wl, t, P4, sb, (const uint4*)(&S2[srow][q2 * 32]), a0, a1,
                a2, a3, a4, a5);
    part[q2][0][jg] = a0;
    part[q2][0][128 + jg] = a3;
    part[q2][1][jg] = a1;
    part[q2][1][128 + jg] = a4;
    part[q2][2][jg] = a2;
    part[q2][2][128 + jg] = a5;
    __syncthreads();
    if (t < 128) {
      float s0r = 0, s1r = 0, s0z = 0, s1z = 0, s0n = 0, s1n = 0;
#pragma unroll
      for (int q = 0; q < 4; ++q) {
        float2 pr = *(const float2*)(&part[q][0][2 * t]); s0r += pr.x; s1r += pr.y;
        float2 pz = *(const float2*)(&part[q][1][2 * t]); s0z += pz.x; s1z += pz.y;
        float2 pn = *(const float2*)(&part[q][2][2 * t]); s0n += pn.x; s1n += pn.y;
      }
      float r0 = sigm(pxr.x + s0r), r1 = sigm(pxr.y + s1r);
      float z0 = sigm(pxz.x + s0z), z1 = sigm(pxz.y + s1z);
      float n0 = tanh_fast(pxn.x + r0 * s0n), n1 = tanh_fast(pxn.y + r1 * s1n);
      float h0 = (1.f - z0) * n0 + z0 * hp0;
      float h1 = (1.f - z1) * n1 + z1 * hp1;
      mx0 = fmaxf(mx0, h0);
      mx1 = fmaxf(mx1, h1);
      if (istd) {
        float2 o;
        o.x = h0;
        o.y = h1;
        *(float2*)(S + idx * 256 + 2 * t) = o;
        S2[idx][t] = packh2(h0, h1);
      } else if (par >= 0) {
        float c0 = acc0 + h0;
        float c1 = acc1 + h1;
        float2 o;
        o.x = c0;
        o.y = c1;
        *(float2*)(S + par * 256 + 2 * t) = o;
        S2[par][t] = packh2(c0, c1);
      }
    }
    __syncthreads();
  }

  if (t < 128) {
    float2 o;
    o.x = mx0;
    o.y = mx1;
    *(float2*)(ctx + (size_t)b * 512 + istd * 256 + 2 * t) = o;
  }
}

// ---- fc1 + fc2 ----
__global__ __launch_bounds__(128) void final_k(const float* __restrict__ ctx_g,
                                               const float* __restrict__ fcW,
                                               const float* __restrict__ fcb,
                                               const float* __restrict__ fc2W,
                                               const float* __restrict__ fc2b,
                                               float* __restrict__ out) {
  const int b = blockIdx.x, t = threadIdx.x;
  __shared__ float ctx[512];
  __shared__ float f1[100];
  for (int i = t; i < 512; i += 128) ctx[i] = ctx_g[(size_t)b * 512 + i];
  __syncthreads();
  if (t < 100) {
    float a = fcb[t];
    for (int k = 0; k < 512; ++k) a = fmaf(ctx[k], fcW[k * 100 + t], a);
    f1[t] = a;
  }
  __syncthreads();
  if (t < 5) {
    float a = fc2b[t];
    for (int k = 0; k < 100; ++k) a = fmaf(f1[k], fc2W[k * 5 + t], a);
    out[b * 5 + t] = a;
  }
}

extern "C" void kernel_launch(void* const* d_in, const int* in_sizes, int n_in, void* d_out,
                              int out_size, void* d_ws, size_t ws_size, hipStream_t stream) {
  const int* xs = (const int*)d_in[0];
  const int* heads = (const int*)d_in[1];
  const int* rels = (const int*)d_in[2];
  const int* labels = (const int*)d_in[3];
  const float* emb_W = (const float*)d_in[9];
  const float* rel_W = (const float*)d_in[10];
  const float* Wi_f = (const float*)d_in[11];
  const float* Wh_f = (const float*)d_in[12];
  const float* bi_f = (const float*)d_in[13];
  const float* bh_f = (const float*)d_in[14];
  const float* Wi_b = (const float*)d_in[15];
  const float* Wh_b = (const float*)d_in[16];
  const float* bi_b = (const float*)d_in[17];
  const float* bh_b = (const float*)d_in[18];
  const float* Wt = (const float*)d_in[19];
  const float* bt = (const float*)d_in[20];
  const float* dt_Wx = (const float*)d_in[21];
  const float* dt_Uh = (const float*)d_in[22];
  const float* dt_b = (const float*)d_in[23];
  const float* td_Wx = (const float*)d_in[24];
  const float* td_Uh = (const float*)d_in[25];
  const float* td_b = (const float*)d_in[26];
  const float* fc_W = (const float*)d_in[27];
  const float* fc_b = (const float*)d_in[28];
  const float* fc2_W = (const float*)d_in[29];
  const float* fc2_b = (const float*)d_in[30];

  float* ws = (float*)d_ws;
  float* xp_f = ws;                          // 1572864 f32
  float* xp_b = ws + 1572864;                // 1572864
  float* grus = ws + 3145728;                // 1048576
  float* ctx = ws + 4194304;                 // 16384
  unsigned* P0 = (unsigned*)(ws + 4210688);  // 98304 u32 each
  unsigned* P1 = P0 + 98304;
  unsigned* P2 = P1 + 98304;
  unsigned* P3 = P2 + 98304;
  unsigned short* embHi = (unsigned short*)(ws + 4603904);  // 1048576 u16
  unsigned short* embLo = (unsigned short*)(ws + 5128192);
  unsigned short* WTh_a = (unsigned short*)(ws + 5652480);  // 393216 u16 each
  unsigned short* WTl_a = (unsigned short*)(ws + 5849088);
  unsigned short* WTh_b = (unsigned short*)(ws + 6045696);
  unsigned short* WTl_b = (unsigned short*)(ws + 6242304);
  unsigned short* outHi = embHi;  // alias (emb dead after xp matmuls)
  unsigned short* outLo = embLo;
  float* Sg = ws + 4603904;       // alias: tree f32 state (emb/out dead by then)

  pack_w<<<dim3(384, 4), 256, 0, stream>>>(Wh_f, Wh_b, dt_Uh, td_Uh, P0, P1, P2, P3);
  tsplit2<<<dim3(24, 16, 2), 256, 0, stream>>>(Wi_f, Wi_b, WTh_a, WTl_a, WTh_b, WTl_b,
                                               512, 768);
  gather_emb_hl<<<2048, 128, 0, stream>>>(xs, labels, emb_W, embHi, embLo);
  mm16p2<<<dim3(12, 32, 2), 256, 0, stream>>>(embHi, embLo, WTh_a, WTl_a, bi_f, xp_f,
                                              WTh_b, WTl_b, bi_b, xp_b, 768);
  gru_scan_h<<<64, 512, 0, stream>>>(P0, P1, bh_f, bh_b, xp_f, xp_b, grus);
  tsplit2<<<dim3(24, 16, 2), 256, 0, stream>>>(dt_Wx, td_Wx, WTh_a, WTl_a, WTh_b, WTl_b,
                                               512, 768);
  mm16s_wt<<<dim3(4, 32), 256, 0, stream>>>(grus, Wt, bt, outHi, outLo, 256, 512);
  gather_rel_hl<<<2048, 64, 0, stream>>>(rels, rel_W, outHi, outLo);
  mm16p2<<<dim3(12, 32, 2), 256, 0, stream>>>(outHi, outLo, WTh_a, WTl_a, dt_b, xp_f,
                                              WTh_b, WTl_b, td_b, xp_b, 768);
  tree_scan_g<<<64, 512, 0, stream>>>(P2, P3, xp_f, xp_b, heads, ctx, Sg);
  final_k<<<32, 128, 0, stream>>>(ctx, fc_W, fc_b, fc2_W, fc2_b, (float*)d_out);
}